// Round 1
// baseline (235.041 us; speedup 1.0000x reference)
//
#include <hip/hip_runtime.h>
#include <hip/hip_bf16.h>
#include <stdint.h>

// Problem constants
#define M_TOK 2048   // B*S
#define N_OUT 4096   // OUT_F
#define K_IN  4096   // IN_F
#define GROUPSZ 128
#define NGRP  32

typedef __bf16 bf16_t;
typedef bf16_t bf16x4 __attribute__((ext_vector_type(4)));
typedef bf16_t bf16x8 __attribute__((ext_vector_type(8)));
typedef float  floatx4 __attribute__((ext_vector_type(4)));

__device__ __forceinline__ bf16_t f2bf(float f) { return (bf16_t)f; }

// ---------------- Kernel 1: x fp32 -> bf16 (4 elems/thread, float4 coalesced)
__global__ __launch_bounds__(256) void convert_x_kernel(
    const float* __restrict__ x, bf16_t* __restrict__ xb) {
  size_t i = ((size_t)blockIdx.x * blockDim.x + threadIdx.x) * 4;
  if (i >= (size_t)M_TOK * K_IN) return;
  float4 a = *(const float4*)(x + i);
  bf16x4 o;
  o.x = f2bf(a.x); o.y = f2bf(a.y); o.z = f2bf(a.z); o.w = f2bf(a.w);
  *(bf16x4*)(xb + i) = o;
}

// ---------------- Kernel 2: w int (int32 per harness) * s_w -> bf16
// w_q flat layout: [o][g][k'] = o*4096 + g*128 + k'  -> row-major (O, K) = B^T
// s_w flat layout: [g][o] = g*4096 + o
__global__ __launch_bounds__(256) void convert_w_kernel(
    const int* __restrict__ wq, const float* __restrict__ sw,
    bf16_t* __restrict__ wb) {
  int t = blockIdx.x * blockDim.x + threadIdx.x;   // 1,048,576 threads
  int o  = t >> 8;              // 256 chunks of 16 per K-row
  int kc = (t & 255) << 4;      // k base, 16 consecutive k (single group: 16|128)
  float s = sw[(kc >> 7) * N_OUT + o];
  const int* src = wq + (size_t)o * K_IN + kc;
  bf16_t tmp[16];
#pragma unroll
  for (int j = 0; j < 16; ++j) tmp[j] = f2bf((float)src[j] * s);
  bf16_t* dst = wb + (size_t)o * K_IN + kc;
  *(bf16x8*)(dst)     = *(bf16x8*)(tmp);
  *(bf16x8*)(dst + 8) = *(bf16x8*)(tmp + 8);
}

// ---------------- Kernel 3: GEMM C = A(2048xK) * Bt(4096xK)^T + bias
// m97 structure: 128x128 tile, BK=64, 4 waves (2x2), 4x4 frags of 16x16x32 bf16,
// global_load_lds width=16 staging.
#define BM 128
#define BN 128
#define BK 64

__global__ __launch_bounds__(256) void gemm_bias_kernel(
    const bf16_t* __restrict__ A, const bf16_t* __restrict__ Bt,
    const float* __restrict__ bias, float* __restrict__ C) {
  __shared__ bf16_t As[BM * BK];   // 16 KB
  __shared__ bf16_t Bs[BN * BK];   // 16 KB

  const int tid  = threadIdx.x;
  const int lane = tid & 63;
  const int wave = tid >> 6;
  const int bm = blockIdx.y;
  const int bn = blockIdx.x;
  const int wm = wave >> 1;        // 0..1
  const int wn = wave & 1;         // 0..1

  const int rowA0 = bm * BM;
  const int rowB0 = bn * BN;

  floatx4 acc[4][4];
#pragma unroll
  for (int i = 0; i < 4; ++i)
#pragma unroll
    for (int j = 0; j < 4; ++j) acc[i][j] = (floatx4)0.0f;

  const int quad = lane >> 4;      // 0..3
  const int l16  = lane & 15;

  for (int k0 = 0; k0 < K_IN; k0 += BK) {
    __syncthreads();   // previous compute done before LDS overwrite
    // Stage A-tile and B-tile: 1024 chunks of 16 B each, 4 per thread.
    // LDS dest is wave-uniform base + lane*16 (global_load_lds constraint):
    // chunk = i*256 + wave*64 + lane  ->  As element offset chunk*8.
#pragma unroll
    for (int i = 0; i < 4; ++i) {
      int chunk = i * 256 + tid;          // tid = wave*64 + lane, wave-contiguous
      int row = chunk >> 3;               // tile row 0..127
      int col = (chunk & 7) << 3;         // k offset 0..56
      const bf16_t* srcA = A  + (size_t)(rowA0 + row) * K_IN + k0 + col;
      const bf16_t* srcB = Bt + (size_t)(rowB0 + row) * K_IN + k0 + col;
      __builtin_amdgcn_global_load_lds(
          (const __attribute__((address_space(1))) void*)srcA,
          (__attribute__((address_space(3))) void*)(As + (size_t)(i * 256 + wave * 64) * 8),
          16, 0, 0);
      __builtin_amdgcn_global_load_lds(
          (const __attribute__((address_space(1))) void*)srcB,
          (__attribute__((address_space(3))) void*)(Bs + (size_t)(i * 256 + wave * 64) * 8),
          16, 0, 0);
    }
    __syncthreads();   // compiler emits vmcnt(0) drain before barrier

#pragma unroll
    for (int kk = 0; kk < BK; kk += 32) {
      bf16x8 af[4], bfr[4];
      const int kcol = kk + quad * 8;
#pragma unroll
      for (int i = 0; i < 4; ++i) {
        int r = wm * 64 + i * 16 + l16;       // m index
        af[i] = *(const bf16x8*)(As + r * BK + kcol);
      }
#pragma unroll
      for (int j = 0; j < 4; ++j) {
        int r = wn * 64 + j * 16 + l16;       // n index
        bfr[j] = *(const bf16x8*)(Bs + r * BK + kcol);
      }
#pragma unroll
      for (int i = 0; i < 4; ++i)
#pragma unroll
        for (int j = 0; j < 4; ++j)
          acc[i][j] = __builtin_amdgcn_mfma_f32_16x16x32_bf16(af[i], bfr[j], acc[i][j], 0, 0, 0);
    }
  }

  // Epilogue: C/D layout col = lane&15 (n), row = quad*4 + reg (m). Fused bias.
#pragma unroll
  for (int j = 0; j < 4; ++j) {
    int col = rowB0 + wn * 64 + j * 16 + l16;
    float bv = bias[col];
#pragma unroll
    for (int i = 0; i < 4; ++i) {
      int rowbase = rowA0 + wm * 64 + i * 16 + quad * 4;
#pragma unroll
      for (int r = 0; r < 4; ++r) {
        C[(size_t)(rowbase + r) * N_OUT + col] = acc[i][j][r] + bv;
      }
    }
  }
}

extern "C" void kernel_launch(void* const* d_in, const int* in_sizes, int n_in,
                              void* d_out, int out_size, void* d_ws, size_t ws_size,
                              hipStream_t stream) {
  const float* x    = (const float*)d_in[0];
  const int*   wq   = (const int*)d_in[1];     // integer input -> int32 per harness
  const float* sw   = (const float*)d_in[2];
  const float* bias = (const float*)d_in[3];
  float* out = (float*)d_out;

  bf16_t* xb = (bf16_t*)d_ws;                                    // 16 MB
  bf16_t* wb = (bf16_t*)((char*)d_ws + (size_t)M_TOK * K_IN * 2); // 32 MB

  {
    int nthreads = M_TOK * K_IN / 4;
    convert_x_kernel<<<nthreads / 256, 256, 0, stream>>>(x, xb);
  }
  {
    int nthreads = N_OUT * K_IN / 16;
    convert_w_kernel<<<nthreads / 256, 256, 0, stream>>>(wq, sw, wb);
  }
  {
    dim3 grid(N_OUT / BN, M_TOK / BM);   // (32, 16) = 512 blocks
    gemm_bias_kernel<<<grid, 256, 0, stream>>>(xb, wb, bias, out);
  }
}

// Round 2
// 211.895 us; speedup vs baseline: 1.1092x; 1.1092x over previous
//
#include <hip/hip_runtime.h>
#include <hip/hip_bf16.h>
#include <stdint.h>

// Problem constants
#define M_TOK 2048   // B*S
#define N_OUT 4096   // OUT_F
#define K_IN  4096   // IN_F
#define GROUPSZ 128
#define NGRP  32

typedef __bf16 bf16_t;
typedef bf16_t bf16x4 __attribute__((ext_vector_type(4)));
typedef bf16_t bf16x8 __attribute__((ext_vector_type(8)));
typedef float  floatx4 __attribute__((ext_vector_type(4)));

__device__ __forceinline__ bf16_t f2bf(float f) { return (bf16_t)f; }

// ---------------- Kernel 1: x fp32 -> bf16 (8 elems/thread, 2x float4 loads)
__global__ __launch_bounds__(256) void convert_x_kernel(
    const float* __restrict__ x, bf16_t* __restrict__ xb) {
  size_t i = ((size_t)blockIdx.x * blockDim.x + threadIdx.x) * 8;
  float4 a = *(const float4*)(x + i);
  float4 b = *(const float4*)(x + i + 4);
  bf16x8 o;
  o[0] = f2bf(a.x); o[1] = f2bf(a.y); o[2] = f2bf(a.z); o[3] = f2bf(a.w);
  o[4] = f2bf(b.x); o[5] = f2bf(b.y); o[6] = f2bf(b.z); o[7] = f2bf(b.w);
  *(bf16x8*)(xb + i) = o;
}

// ---------------- Kernel 2: w int32 * s_w -> bf16 (4 elems/thread, int4 load)
// w_q flat layout: [o][g][k'] = o*4096 + g*128 + k'  -> row-major (O, K) = B^T
// s_w flat layout: [g][o] = g*4096 + o
__global__ __launch_bounds__(256) void convert_w_kernel(
    const int* __restrict__ wq, const float* __restrict__ sw,
    bf16_t* __restrict__ wb) {
  size_t t = (size_t)blockIdx.x * blockDim.x + threadIdx.x; // 4M threads
  int o  = (int)(t >> 10);            // 1024 chunks of 4 per K-row
  int kc = ((int)t & 1023) << 2;      // k base, 4 consecutive k (same group)
  float s = sw[(kc >> 7) * N_OUT + o];
  int4 a = *(const int4*)(wq + (size_t)o * K_IN + kc);
  bf16x4 ov;
  ov[0] = f2bf((float)a.x * s);
  ov[1] = f2bf((float)a.y * s);
  ov[2] = f2bf((float)a.z * s);
  ov[3] = f2bf((float)a.w * s);
  *(bf16x4*)(wb + (size_t)o * K_IN + kc) = ov;
}

// ---------------- Kernel 3: GEMM C = A(2048xK) * Bt(4096xK)^T + bias
// m97 structure: 128x128 tile, BK=64, 4 waves (2x2), 4x4 frags of 16x16x32 bf16,
// global_load_lds width=16 staging, XOR-swizzled LDS chunk layout.
//
// Swizzle: LDS 16B-chunk (row, c) holds global k-chunk (row, c ^ (row&7)).
// Read side: addr/4 % 32 = ((c ^ (l16&7))*4) -> all 32 banks, 8 lanes/group
// = the 8-cycle wave64 b128 floor (was 16-way conflict on 4-bank groups).
#define BM 128
#define BN 128
#define BK 64

__global__ __launch_bounds__(256) void gemm_bias_kernel(
    const bf16_t* __restrict__ A, const bf16_t* __restrict__ Bt,
    const float* __restrict__ bias, float* __restrict__ C) {
  __shared__ bf16_t As[BM * BK];   // 16 KB
  __shared__ bf16_t Bs[BN * BK];   // 16 KB

  const int tid  = threadIdx.x;
  const int lane = tid & 63;
  const int wave = tid >> 6;
  const int bm = blockIdx.y;
  const int bn = blockIdx.x;
  const int wm = wave >> 1;        // 0..1
  const int wn = wave & 1;         // 0..1

  const int rowA0 = bm * BM;
  const int rowB0 = bn * BN;

  floatx4 acc[4][4];
#pragma unroll
  for (int i = 0; i < 4; ++i)
#pragma unroll
    for (int j = 0; j < 4; ++j) acc[i][j] = (floatx4)0.0f;

  const int quad = lane >> 4;      // 0..3
  const int l16  = lane & 15;

  for (int k0 = 0; k0 < K_IN; k0 += BK) {
    __syncthreads();   // previous compute done before LDS overwrite
    // Stage A-tile and B-tile: 1024 chunks of 16 B each, 4 per thread.
    // LDS dest is wave-uniform base + lane*16 (global_load_lds constraint).
    // Global source column is XOR-swizzled so reads are conflict-free.
#pragma unroll
    for (int i = 0; i < 4; ++i) {
      int chunk = i * 256 + tid;            // tid = wave*64 + lane, wave-contiguous
      int row = chunk >> 3;                 // tile row 0..127
      int csw = (chunk & 7) ^ (row & 7);    // swizzled k-chunk 0..7
      int col = csw << 3;                   // k elem offset 0..56
      const bf16_t* srcA = A  + (size_t)(rowA0 + row) * K_IN + k0 + col;
      const bf16_t* srcB = Bt + (size_t)(rowB0 + row) * K_IN + k0 + col;
      __builtin_amdgcn_global_load_lds(
          (const __attribute__((address_space(1))) void*)srcA,
          (__attribute__((address_space(3))) void*)(As + (size_t)(i * 256 + wave * 64) * 8),
          16, 0, 0);
      __builtin_amdgcn_global_load_lds(
          (const __attribute__((address_space(1))) void*)srcB,
          (__attribute__((address_space(3))) void*)(Bs + (size_t)(i * 256 + wave * 64) * 8),
          16, 0, 0);
    }
    __syncthreads();   // compiler emits vmcnt(0) drain before barrier

#pragma unroll
    for (int kk = 0; kk < BK; kk += 32) {
      bf16x8 af[4], bfr[4];
      const int kc8 = (kk >> 3) + quad;     // k-chunk index 0..7
#pragma unroll
      for (int i = 0; i < 4; ++i) {
        int r = wm * 64 + i * 16 + l16;     // m index; r&7 == l16&7
        af[i] = *(const bf16x8*)(As + (size_t)(r * 8 + (kc8 ^ (r & 7))) * 8);
      }
#pragma unroll
      for (int j = 0; j < 4; ++j) {
        int r = wn * 64 + j * 16 + l16;     // n index
        bfr[j] = *(const bf16x8*)(Bs + (size_t)(r * 8 + (kc8 ^ (r & 7))) * 8);
      }
#pragma unroll
      for (int i = 0; i < 4; ++i)
#pragma unroll
        for (int j = 0; j < 4; ++j)
          acc[i][j] = __builtin_amdgcn_mfma_f32_16x16x32_bf16(af[i], bfr[j], acc[i][j], 0, 0, 0);
    }
  }

  // Epilogue: C/D layout col = lane&15 (n), row = quad*4 + reg (m). Fused bias.
#pragma unroll
  for (int j = 0; j < 4; ++j) {
    int col = rowB0 + wn * 64 + j * 16 + l16;
    float bv = bias[col];
#pragma unroll
    for (int i = 0; i < 4; ++i) {
      int rowbase = rowA0 + wm * 64 + i * 16 + quad * 4;
#pragma unroll
      for (int r = 0; r < 4; ++r) {
        C[(size_t)(rowbase + r) * N_OUT + col] = acc[i][j][r] + bv;
      }
    }
  }
}

extern "C" void kernel_launch(void* const* d_in, const int* in_sizes, int n_in,
                              void* d_out, int out_size, void* d_ws, size_t ws_size,
                              hipStream_t stream) {
  const float* x    = (const float*)d_in[0];
  const int*   wq   = (const int*)d_in[1];     // integer input -> int32 per harness
  const float* sw   = (const float*)d_in[2];
  const float* bias = (const float*)d_in[3];
  float* out = (float*)d_out;

  bf16_t* xb = (bf16_t*)d_ws;                                     // 16 MB
  bf16_t* wb = (bf16_t*)((char*)d_ws + (size_t)M_TOK * K_IN * 2); // 32 MB

  {
    int nthreads = M_TOK * K_IN / 8;            // 1M threads
    convert_x_kernel<<<nthreads / 256, 256, 0, stream>>>(x, xb);
  }
  {
    int nthreads = N_OUT * K_IN / 4;            // 4M threads
    convert_w_kernel<<<nthreads / 256, 256, 0, stream>>>(wq, sw, wb);
  }
  {
    dim3 grid(N_OUT / BN, M_TOK / BM);          // (32, 16) = 512 blocks
    gemm_bias_kernel<<<grid, 256, 0, stream>>>(xb, wb, bias, out);
  }
}